// Round 7
// baseline (96.753 us; speedup 1.0000x reference)
//
#include <hip/hip_runtime.h>
#include <hip/hip_bf16.h>

typedef __attribute__((ext_vector_type(8))) short bf16x8;
typedef __attribute__((ext_vector_type(4))) float f32x4;

#define NB 512
#define FD 512

// ws layout (32-bit words):
//   [0]      cnt_ref  — NEVER written; read as base B (works for any uniform
//                       initial fill: 0xAA poison, zero-init, ...; wrap-safe)
//   [8+m]    cnt_m    — stripe-completion counters, m = 0..15
//   [24]     cnt_g    — grid-completion counter
//   [32+m]   partial_m (float) — per-stripe contrib sums
//   word 1024+ : sim (512x512 f32, 1 MB)
// Re-poison to 0xAA before every launch (documented + observed as the 41 us
// fills) resets all counters to the same uniform base each call.

// ---------------------------------------------------------------------------
// cvt8: 8 consecutive fp32 -> bf16 hi plane + bf16 lo plane (3-term split:
// hi*hi + hi*lo + lo*hi recovers ~fp32 accuracy; absmax 0.0 in R3..R6).
// ---------------------------------------------------------------------------
__device__ __forceinline__ void cvt8(const float* __restrict__ p,
                                     bf16x8& hi, bf16x8& lo)
{
    const float4 u = *(const float4*)p;
    const float4 v = *(const float4*)(p + 4);
    const float x[8] = {u.x, u.y, u.z, u.w, v.x, v.y, v.z, v.w};
    #pragma unroll
    for (int i = 0; i < 8; ++i) {
        const __hip_bfloat16 h = __float2bfloat16(x[i]);
        hi[i] = __builtin_bit_cast(short, h);
        const float r = x[i] - __bfloat162float(h);
        lo[i] = __builtin_bit_cast(short, __float2bfloat16(r));
    }
}

// ---------------------------------------------------------------------------
// k_fused: GEMM tile (as R6 k_mm: 256 blocks x 256 thr, intra-block split-K,
// LDS reduce, single sim write) + fused rank tail via threadfence-reduction:
// the last-arriving block of each 32-row stripe ranks those rows; the last
// block of the grid sums the 16 stripe partials and writes the scalar.
// ---------------------------------------------------------------------------
__global__ __launch_bounds__(256)
void k_fused(const float* __restrict__ fs, const float* __restrict__ ft,
             float* __restrict__ wsf, float* __restrict__ out1)
{
    uint*  wsu = (uint*)wsf;
    float* sim = wsf + 1024;                 // byte offset 4096

    __shared__ f32x4 red[3][64][4];          // waves 1..3 partial accs
    __shared__ float part[4];
    __shared__ uint  flag;

    const int tid = threadIdx.x;
    const int l   = tid & 63;
    const int w   = tid >> 6;                // k-quarter / rank-wave 0..3
    const int bid = blockIdx.x;              // 16 x 16 tiles of 32x32
    const int m   = bid >> 4;                // row-stripe 0..15
    const int tr  = m * 32;
    const int tc  = (bid & 15) * 32;
    const int r0  = l & 15;
    const int kg  = w * 128 + (l >> 4) * 8;  // this lane's k base

    // ---- GEMM phase (identical math to R6) ----
    const float* pa0 = fs + (size_t)(tr + r0)      * FD + kg;
    const float* pa1 = fs + (size_t)(tr + r0 + 16) * FD + kg;
    const float* pb0 = ft + (size_t)(tc + r0)      * FD + kg;
    const float* pb1 = ft + (size_t)(tc + r0 + 16) * FD + kg;

    f32x4 acc[2][2];
    #pragma unroll
    for (int i = 0; i < 2; ++i)
        #pragma unroll
        for (int j = 0; j < 2; ++j) acc[i][j] = (f32x4){0.f, 0.f, 0.f, 0.f};

    #pragma unroll
    for (int k = 0; k < 128; k += 32) {
        bf16x8 a0h, a0l, a1h, a1l, b0h, b0l, b1h, b1l;
        cvt8(pa0 + k, a0h, a0l);
        cvt8(pa1 + k, a1h, a1l);
        cvt8(pb0 + k, b0h, b0l);
        cvt8(pb1 + k, b1h, b1l);

        acc[0][0] = __builtin_amdgcn_mfma_f32_16x16x32_bf16(a0h, b0h, acc[0][0], 0, 0, 0);
        acc[0][0] = __builtin_amdgcn_mfma_f32_16x16x32_bf16(a0h, b0l, acc[0][0], 0, 0, 0);
        acc[0][0] = __builtin_amdgcn_mfma_f32_16x16x32_bf16(a0l, b0h, acc[0][0], 0, 0, 0);
        acc[0][1] = __builtin_amdgcn_mfma_f32_16x16x32_bf16(a0h, b1h, acc[0][1], 0, 0, 0);
        acc[0][1] = __builtin_amdgcn_mfma_f32_16x16x32_bf16(a0h, b1l, acc[0][1], 0, 0, 0);
        acc[0][1] = __builtin_amdgcn_mfma_f32_16x16x32_bf16(a0l, b1h, acc[0][1], 0, 0, 0);
        acc[1][0] = __builtin_amdgcn_mfma_f32_16x16x32_bf16(a1h, b0h, acc[1][0], 0, 0, 0);
        acc[1][0] = __builtin_amdgcn_mfma_f32_16x16x32_bf16(a1h, b0l, acc[1][0], 0, 0, 0);
        acc[1][0] = __builtin_amdgcn_mfma_f32_16x16x32_bf16(a1l, b0h, acc[1][0], 0, 0, 0);
        acc[1][1] = __builtin_amdgcn_mfma_f32_16x16x32_bf16(a1h, b1h, acc[1][1], 0, 0, 0);
        acc[1][1] = __builtin_amdgcn_mfma_f32_16x16x32_bf16(a1h, b1l, acc[1][1], 0, 0, 0);
        acc[1][1] = __builtin_amdgcn_mfma_f32_16x16x32_bf16(a1l, b1h, acc[1][1], 0, 0, 0);
    }

    // intra-block split-K reduction: waves 1..3 park accs in LDS, wave 0 sums
    if (w != 0) {
        red[w - 1][l][0] = acc[0][0];
        red[w - 1][l][1] = acc[0][1];
        red[w - 1][l][2] = acc[1][0];
        red[w - 1][l][3] = acc[1][1];
    }
    __syncthreads();
    if (w == 0) {
        #pragma unroll
        for (int u = 0; u < 3; ++u) {
            acc[0][0] += red[u][l][0];
            acc[0][1] += red[u][l][1];
            acc[1][0] += red[u][l][2];
            acc[1][1] += red[u][l][3];
        }
        const int rbase = (l >> 4) * 4;
        #pragma unroll
        for (int mh = 0; mh < 2; ++mh)
            #pragma unroll
            for (int j = 0; j < 4; ++j) {
                const int row = tr + mh * 16 + rbase + j;
                sim[(size_t)row * NB + tc + r0]      = acc[mh][0][j];
                sim[(size_t)row * NB + tc + 16 + r0] = acc[mh][1][j];
            }
    }
    __syncthreads();                 // drains wave-0 store vmcnt before fence

    // ---- stripe-completion: release sim tile, detect stripe-last block ----
    if (tid == 0) {
        __threadfence();                                   // release (wbl2)
        const uint B   = *(volatile const uint*)(wsu + 0); // uniform base
        const uint old = atomicAdd(wsu + 8 + m, 1u);
        flag = (old == B + 15u) ? 1u : 0u;
    }
    __syncthreads();

    if (flag) {
        __threadfence();             // acquire: invalidate stale caches
        // rank stripe m's 32 rows: wave w handles rows m*32 + w*8 .. +7
        float wacc = 0.f;
        for (int rr = 0; rr < 8; ++rr) {
            const int b = tr + w * 8 + rr;
            const int n = b >> 3;                    // identity group
            const float* p = sim + (size_t)b * NB + 8 * l;
            const float4 u = *(const float4*)(p);
            const float4 v = *(const float4*)(p + 4);
            float r[8] = {u.x, u.y, u.z, u.w, v.x, v.y, v.z, v.w};

            float s[8];
            #pragma unroll
            for (int q = 0; q < 8; ++q) s[q] = __shfl(r[q], n);

            float a[8];
            #pragma unroll
            for (int q = 0; q < 8; ++q) a[q] = 0.f;
            #pragma unroll
            for (int q = 0; q < 8; ++q)
                #pragma unroll
                for (int jj = 0; jj < 8; ++jj)
                    a[q] += fmaxf(r[jj] - s[q], 0.f);

            #pragma unroll
            for (int off = 1; off < 64; off <<= 1)
                #pragma unroll
                for (int q = 0; q < 8; ++q)
                    a[q] += __shfl_xor(a[q], off);

            float c = 0.f;
            if (l < 8) {
                float rp = 1.f;
                #pragma unroll
                for (int k = 0; k < 8; ++k) rp += fmaxf(s[k] - s[l], 0.f);
                c = rp / (1.f + a[l]);
            }
            c += __shfl_xor(c, 1);
            c += __shfl_xor(c, 2);
            c += __shfl_xor(c, 4);
            if (l == 0) wacc += c;
        }
        if (l == 0) part[w] = wacc;
        __syncthreads();
        if (tid == 0) {
            wsf[32 + m] = part[0] + part[1] + part[2] + part[3];
            __threadfence();         // release partial_m before cnt_g add
        }
    }

    // ---- grid-completion: 256th incrementer writes the scalar ----
    if (tid == 0) {
        const uint B    = *(volatile const uint*)(wsu + 0);
        const uint oldg = atomicAdd(wsu + 24, 1u);
        if (oldg == B + 255u) {
            __threadfence();         // acquire: all 16 partials visible
            float t = 0.f;
            #pragma unroll
            for (int i = 0; i < 16; ++i) t += wsf[32 + i];
            out1[0] = 1.f - t * (1.f / (8.f * NB));
        }
    }
}

// ---------------------------------------------------------------------------
extern "C" void kernel_launch(void* const* d_in, const int* in_sizes, int n_in,
                              void* d_out, int out_size, void* d_ws, size_t ws_size,
                              hipStream_t stream)
{
    const float* fs = (const float*)d_in[0];   // f_s (512x512 f32)
    const float* ft = (const float*)d_in[1];   // f_t (512x512 f32)
    float* out = (float*)d_out;                // scalar f32
    float* wsf = (float*)d_ws;                 // counters + partials + sim

    k_fused<<<dim3(256), dim3(256), 0, stream>>>(fs, ft, wsf, out);
}

// Round 8
// 63.039 us; speedup vs baseline: 1.5348x; 1.5348x over previous
//
#include <hip/hip_runtime.h>
#include <hip/hip_bf16.h>

typedef __attribute__((ext_vector_type(8))) short bf16x8;
typedef __attribute__((ext_vector_type(4))) float f32x4;

#define NB 512
#define FD 512

// ---------------------------------------------------------------------------
// cvt8: 8 consecutive fp32 -> bf16 hi plane + bf16 lo plane (3-term split:
// hi*hi + hi*lo + lo*hi recovers ~fp32 accuracy; absmax 0.0 in R3/R4/R5/R6).
// __float2bfloat16 lets the compiler emit packed v_cvt_pk_bf16_f32 (m240).
// ---------------------------------------------------------------------------
__device__ __forceinline__ void cvt8(const float* __restrict__ p,
                                     bf16x8& hi, bf16x8& lo)
{
    const float4 u = *(const float4*)p;
    const float4 v = *(const float4*)(p + 4);
    const float x[8] = {u.x, u.y, u.z, u.w, v.x, v.y, v.z, v.w};
    #pragma unroll
    for (int i = 0; i < 8; ++i) {
        const __hip_bfloat16 h = __float2bfloat16(x[i]);
        hi[i] = __builtin_bit_cast(short, h);
        const float r = x[i] - __bfloat162float(h);
        lo[i] = __builtin_bit_cast(short, __float2bfloat16(r));
    }
}

// ---------------------------------------------------------------------------
// k_mm: sim = fs @ ft^T via mfma_f32_16x16x32_bf16, fused fp32->bf16 hi/lo
// conversion, split-K INSIDE the block: 256 blocks (one 32x32 tile each) x
// 256 threads = 4 waves, wave w owns k-quarter [128w, 128w+128). 1 block/CU
// x 4 waves keeps the R4-verified L2 latency hiding; the K-partials are
// reduced in LDS (12 KB, one barrier) so sim is written exactly once (1 MB,
// no slice round-trip). No LDS in the MFMA loop itself.
// NOTE (R7): do NOT fuse the rank tail into this kernel via threadfence-
// reduction — device-scope fences on non-coherent per-XCD L2s cost ~50 us
// (measured R7: 52 us fused vs ~3.5 us for two kernels).
// Frag layout (verified m89/m91): A/B lane l = row (l&15), k = 8*(l>>4)+i;
// C/D: col = l&15, row = (l>>4)*4 + reg.
// ---------------------------------------------------------------------------
__global__ __launch_bounds__(256)
void k_mm(const float* __restrict__ fs, const float* __restrict__ ft,
          float* __restrict__ sim, float* __restrict__ out1)
{
    __shared__ f32x4 red[3][64][4];          // waves 1..3 partial accs

    const int tid = threadIdx.x;
    const int l   = tid & 63;
    const int w   = tid >> 6;                // k-quarter 0..3
    const int bid = blockIdx.x;              // 16 x 16 tiles of 32x32
    const int tr  = (bid >> 4) * 32;
    const int tc  = (bid & 15) * 32;
    const int r0  = l & 15;
    const int kg  = w * 128 + (l >> 4) * 8;  // this lane's k base

    if (bid == 0 && tid == 0) out1[0] = 1.0f;   // k_rank accumulates -ap

    const float* pa0 = fs + (size_t)(tr + r0)      * FD + kg;
    const float* pa1 = fs + (size_t)(tr + r0 + 16) * FD + kg;
    const float* pb0 = ft + (size_t)(tc + r0)      * FD + kg;
    const float* pb1 = ft + (size_t)(tc + r0 + 16) * FD + kg;

    f32x4 acc[2][2];
    #pragma unroll
    for (int i = 0; i < 2; ++i)
        #pragma unroll
        for (int j = 0; j < 2; ++j) acc[i][j] = (f32x4){0.f, 0.f, 0.f, 0.f};

    #pragma unroll
    for (int k = 0; k < 128; k += 32) {
        bf16x8 a0h, a0l, a1h, a1l, b0h, b0l, b1h, b1l;
        cvt8(pa0 + k, a0h, a0l);
        cvt8(pa1 + k, a1h, a1l);
        cvt8(pb0 + k, b0h, b0l);
        cvt8(pb1 + k, b1h, b1l);

        acc[0][0] = __builtin_amdgcn_mfma_f32_16x16x32_bf16(a0h, b0h, acc[0][0], 0, 0, 0);
        acc[0][0] = __builtin_amdgcn_mfma_f32_16x16x32_bf16(a0h, b0l, acc[0][0], 0, 0, 0);
        acc[0][0] = __builtin_amdgcn_mfma_f32_16x16x32_bf16(a0l, b0h, acc[0][0], 0, 0, 0);
        acc[0][1] = __builtin_amdgcn_mfma_f32_16x16x32_bf16(a0h, b1h, acc[0][1], 0, 0, 0);
        acc[0][1] = __builtin_amdgcn_mfma_f32_16x16x32_bf16(a0h, b1l, acc[0][1], 0, 0, 0);
        acc[0][1] = __builtin_amdgcn_mfma_f32_16x16x32_bf16(a0l, b1h, acc[0][1], 0, 0, 0);
        acc[1][0] = __builtin_amdgcn_mfma_f32_16x16x32_bf16(a1h, b0h, acc[1][0], 0, 0, 0);
        acc[1][0] = __builtin_amdgcn_mfma_f32_16x16x32_bf16(a1h, b0l, acc[1][0], 0, 0, 0);
        acc[1][0] = __builtin_amdgcn_mfma_f32_16x16x32_bf16(a1l, b0h, acc[1][0], 0, 0, 0);
        acc[1][1] = __builtin_amdgcn_mfma_f32_16x16x32_bf16(a1h, b1h, acc[1][1], 0, 0, 0);
        acc[1][1] = __builtin_amdgcn_mfma_f32_16x16x32_bf16(a1h, b1l, acc[1][1], 0, 0, 0);
        acc[1][1] = __builtin_amdgcn_mfma_f32_16x16x32_bf16(a1l, b1h, acc[1][1], 0, 0, 0);
    }

    // intra-block split-K reduction: waves 1..3 park accs in LDS, wave 0 sums
    if (w != 0) {
        red[w - 1][l][0] = acc[0][0];
        red[w - 1][l][1] = acc[0][1];
        red[w - 1][l][2] = acc[1][0];
        red[w - 1][l][3] = acc[1][1];
    }
    __syncthreads();
    if (w == 0) {
        #pragma unroll
        for (int u = 0; u < 3; ++u) {
            acc[0][0] += red[u][l][0];
            acc[0][1] += red[u][l][1];
            acc[1][0] += red[u][l][2];
            acc[1][1] += red[u][l][3];
        }
        // store: row = tr + mh*16 + (l>>4)*4 + j, col = tc + nh*16 + r0
        const int rbase = (l >> 4) * 4;
        #pragma unroll
        for (int mh = 0; mh < 2; ++mh)
            #pragma unroll
            for (int j = 0; j < 4; ++j) {
                const int row = tr + mh * 16 + rbase + j;
                sim[(size_t)row * NB + tc + r0]      = acc[mh][0][j];
                sim[(size_t)row * NB + tc + 16 + r0] = acc[mh][1][j];
            }
    }
}

// ---------------------------------------------------------------------------
// k_rank: per-row rank reduction + SmoothAP term (single sim slice).
// 128 blocks x 256 threads (4 waves, one row per wave; 512 rows total).
// Lane l owns columns 8l..8l+7; lane n (= b>>3) holds the in-group sims.
// Block-reduces 4 wave contribs in LDS -> ONE atomic per block (128 total).
// ---------------------------------------------------------------------------
__global__ __launch_bounds__(256)
void k_rank(const float* __restrict__ sim, float* __restrict__ out1)
{
    __shared__ float part[4];
    const int w = threadIdx.x >> 6;            // wave 0..3 within block
    const int l = threadIdx.x & 63;
    const int b = blockIdx.x * 4 + w;          // row 0..511
    const int n = b >> 3;                      // identity group

    const float* p = sim + (size_t)b * NB + 8 * l;
    const float4 u = *(const float4*)(p);
    const float4 v = *(const float4*)(p + 4);
    float r[8] = {u.x, u.y, u.z, u.w, v.x, v.y, v.z, v.w};

    // s[q] = sim[b, 8n+q]: lane n holds exactly those 8 values
    float s[8];
    #pragma unroll
    for (int q = 0; q < 8; ++q) s[q] = __shfl(r[q], n);

    // per-lane partial rank_all sums over this lane's 8 columns
    float a[8];
    #pragma unroll
    for (int q = 0; q < 8; ++q) a[q] = 0.f;
    #pragma unroll
    for (int q = 0; q < 8; ++q)
        #pragma unroll
        for (int jj = 0; jj < 8; ++jj)
            a[q] += fmaxf(r[jj] - s[q], 0.f);

    // 64-lane butterfly reduce
    #pragma unroll
    for (int off = 1; off < 64; off <<= 1)
        #pragma unroll
        for (int q = 0; q < 8; ++q)
            a[q] += __shfl_xor(a[q], off);

    float contrib = 0.f;
    if (l < 8) {
        float rp = 1.f;
        #pragma unroll
        for (int k = 0; k < 8; ++k) rp += fmaxf(s[k] - s[l], 0.f);
        contrib = rp / (1.f + a[l]);
    }
    contrib += __shfl_xor(contrib, 1);
    contrib += __shfl_xor(contrib, 2);
    contrib += __shfl_xor(contrib, 4);
    if (l == 0) part[w] = contrib;
    __syncthreads();

    if (threadIdx.x == 0) {
        float t = part[0] + part[1] + part[2] + part[3];
        atomicAdd(out1, -t * (1.f / (8.f * NB)));
    }
}

// ---------------------------------------------------------------------------
extern "C" void kernel_launch(void* const* d_in, const int* in_sizes, int n_in,
                              void* d_out, int out_size, void* d_ws, size_t ws_size,
                              hipStream_t stream)
{
    const float* fs = (const float*)d_in[0];   // f_s (512x512 f32)
    const float* ft = (const float*)d_in[1];   // f_t (512x512 f32)
    float* out = (float*)d_out;                // scalar f32
    float* sim = (float*)d_ws;                 // 512*512 f32 = 1 MB

    k_mm  <<<dim3(256), dim3(256), 0, stream>>>(fs, ft, sim, out);
    k_rank<<<dim3(128), dim3(256), 0, stream>>>(sim, out);
}